// Round 11
// baseline (405.362 us; speedup 1.0000x reference)
//
#include <hip/hip_runtime.h>

typedef unsigned short u16;
typedef unsigned int u32;
typedef __attribute__((ext_vector_type(8))) short short8;    // 8 bf16
typedef __attribute__((ext_vector_type(16))) float f32x16;

#define BB 8
#define NN 4096
#define NPP 1024
#define NSS 32
#define CFF 64
#define C0 67
#define H0 64
#define H1 128
#define H2 256
#define NTOT (BB*NN)        // 32768 points
#define MTOT (BB*NPP*NSS)   // 262144
#define BN_EPS 1e-5f
#define INV_M (1.0f/262144.0f)
#define NSLOT 64
#define SQOFF 16384         // 64 slots * 256 ch
#define LSTRIDE 32768       // floats per layer (sum + sq)

#define MFMA32(a,b,c) __builtin_amdgcn_mfma_f32_32x32x16_bf16(a,b,c,0,0,0)

__device__ __forceinline__ float bf2f(u16 h){ return __uint_as_float(((u32)h)<<16); }
__device__ __forceinline__ u16 f2bf(float f){
  u32 u = __float_as_uint(f);
  u32 r = (u + 0x7fffu + ((u>>16)&1u)) >> 16;
  return (u16)r;
}
__device__ __forceinline__ u32 pack2(float a, float b){
  return (u32)f2bf(a) | ((u32)f2bf(b)<<16);
}

// ---------------------------------------------------------------------------
// R11: R10 hybrid with structural slimming.
//  - k_init = uv GEMM (W0 packed inline to LDS) + newxyz + W1/W2 packing.
//  - k_fin folded into producers: last-block-done ticket (counters zeroed by
//    the memset each call), coherent atomicAdd(p,0.f) reads.
//  - l2f LDS 50->42.8 KB (W2 staged in 16KB quarters) -> 3 blocks/CU.
//
// ws layout (bytes), total 42,424,576:
//   cnt   [0,256)             3 u32 tickets (zeroed)
//   stats [256,393472)        3 layers x [64][256] sum + [64][256] sq f32 (zeroed)
//   Wt1c  [393472,409856)     [8][128][8] bf16
//   Wt2c  [409856,475392)     [16][256][8] bf16
//   bnc   [475392,481536)     6 x 256 f32
//   U     [481536,4675840)    (NTOT,64) bf16  -- dead after s0y; mxp aliases
//   T     [4675840,8870144)   (NTOT,64) bf16  -- dead after s0y; mnp aliases
//   y0    [8870144,42424576)  (MTOT,64) bf16
// ---------------------------------------------------------------------------
#define WS_NEED 42424576u

__global__ __launch_bounds__(256) void k_xyz_only(
    const float* __restrict__ xyz, const int* __restrict__ sidx, float* __restrict__ out_newxyz)
{
  int t0 = blockIdx.x*256 + threadIdx.x;
  int b = t0 >> 10;
  int s = sidx[t0];
  for (int k = 0; k < 3; ++k)
    out_newxyz[(size_t)t0*3 + k] = xyz[((size_t)(b*NN + s))*3 + k];
}

// ---------------------------------------------------------------------------
// init: blocks 0..255 = per-point UV GEMM (W0 packed inline); 256..287 newxyz;
// 288 = W1 pack; 289..296 = W2 pack. Grid 297.
// ---------------------------------------------------------------------------
__global__ __launch_bounds__(256) void k_init(
    const float* __restrict__ xyz, const float* __restrict__ points,
    const int* __restrict__ sidx,
    const float* __restrict__ W0, const float* __restrict__ W1, const float* __restrict__ W2,
    u16* __restrict__ Wt1c, u16* __restrict__ Wt2c,
    u16* __restrict__ U, u16* __restrict__ T, float* __restrict__ out_newxyz)
{
  int blk = blockIdx.x, tid = threadIdx.x;
  if (blk >= 256) {
    if (blk < 288) {
      int t0 = (blk - 256)*256 + tid;          // b*NP + p
      int b = t0 >> 10;
      int s = sidx[t0];
      for (int k = 0; k < 3; ++k)
        out_newxyz[(size_t)t0*3 + k] = xyz[((size_t)(b*NN + s))*3 + k];
    } else if (blk == 288) {
      for (int i = 0; i < 32; ++i) {
        int e = i*256 + tid;                   // [8 kc][128 n][8 j]
        int kc = e >> 10, n = (e >> 3) & 127, j = e & 7;
        Wt1c[e] = f2bf(W1[n*H0 + kc*8 + j]);
      }
    } else {
      int base = (blk - 289) * 4096;           // blocks 289..296
      for (int i = 0; i < 16; ++i) {
        int e = base + i*256 + tid;            // [16 kc][256 n][8 j]
        int kc = e >> 11, n = (e >> 3) & 255, j = e & 7;
        Wt2c[e] = f2bf(W2[n*H1 + kc*8 + j]);
      }
    }
    return;
  }

  // ---- UV: per-point GEMM, 128 points/block. K=80 (10 chunks). ----
  __shared__ u16 XLc[10*128*8];  // 20 KB
  __shared__ u16 W0c[10*64*8];   // 10 KB
  int gn0 = blk * 128;
  int b = gn0 >> 12;
  int n0 = gn0 & 4095;

  // inline W0 pack: kc 0..7 = feat (W0 col 3+k), kc 8 = xyz cols 0..2, kc 9 = 0
  for (int i = 0; i < 20; ++i) {
    int e = i*256 + tid;
    if (e < 5120) {
      int kc = e >> 9, o = (e >> 3) & 63, j = e & 7;
      float v;
      if (kc < 8)       v = W0[o*C0 + 3 + kc*8 + j];
      else if (kc == 8) v = (j < 3) ? W0[o*C0 + j] : 0.f;
      else              v = 0.f;
      W0c[e] = f2bf(v);
    }
  }
  {
    int c = tid >> 2, nseg = tid & 3;        // 64 ch x 4 n-segments
    const float* src = points + ((size_t)(b*CFF + c))*NN + n0 + nseg*32;
    int cb = c >> 3, cr = c & 7;
    for (int t = 0; t < 8; ++t) {
      float4 v = *(const float4*)(src + t*4);
      int n = nseg*32 + t*4;
      XLc[(cb*128 + n+0)*8 + cr] = f2bf(v.x);
      XLc[(cb*128 + n+1)*8 + cr] = f2bf(v.y);
      XLc[(cb*128 + n+2)*8 + cr] = f2bf(v.z);
      XLc[(cb*128 + n+3)*8 + cr] = f2bf(v.w);
    }
  }
  if (tid < 128) {
    int gn = gn0 + tid;
    float x = xyz[(size_t)gn*3+0], y = xyz[(size_t)gn*3+1], z = xyz[(size_t)gn*3+2];
    uint4 v = { pack2(x,y), pack2(z,0.f), 0u, 0u };
    *(uint4*)&XLc[(8*128 + tid)*8] = v;
  } else {
    uint4 z4 = {0u,0u,0u,0u};
    *(uint4*)&XLc[(9*128 + (tid-128))*8] = z4;
  }
  __syncthreads();

  int lane = tid & 63, wv = tid >> 6, l31 = lane & 31, kh = lane >> 5;
  int nt = wv & 1, mtb = (wv >> 1)*2;
  f32x16 accT2[2], accU2[2];
  for (int mi = 0; mi < 2; ++mi) for (int r = 0; r < 16; ++r) accT2[mi][r] = 0.f;

  {
    int ck = 8 + kh;
    short8 bfrag = *(const short8*)&W0c[(ck*64 + nt*32 + l31)*8];
    for (int mi = 0; mi < 2; ++mi) {
      short8 afrag = *(const short8*)&XLc[(ck*128 + (mtb+mi)*32 + l31)*8];
      accT2[mi] = MFMA32(afrag, bfrag, accT2[mi]);
    }
  }
  for (int mi = 0; mi < 2; ++mi) accU2[mi] = accT2[mi];
  for (int kt = 0; kt < 4; ++kt) {
    int ck = kt*2 + kh;
    short8 bfrag = *(const short8*)&W0c[(ck*64 + nt*32 + l31)*8];
    for (int mi = 0; mi < 2; ++mi) {
      short8 afrag = *(const short8*)&XLc[(ck*128 + (mtb+mi)*32 + l31)*8];
      accU2[mi] = MFMA32(afrag, bfrag, accU2[mi]);
    }
  }

  int c = nt*32 + l31;
  for (int mi = 0; mi < 2; ++mi)
    for (int r = 0; r < 16; ++r) {
      int gm = gn0 + (mtb+mi)*32 + (r&3) + 8*(r>>2) + 4*kh;
      U[(size_t)gm*64 + c] = f2bf(accU2[mi][r]);
      T[(size_t)gm*64 + c] = f2bf(accT2[mi][r]);
    }
}

// ---------------------------------------------------------------------------
// s0y: THE gather pass. d = U[nb]-T[sp] -> y0 bf16 (coalesced) + stats0.
// Last block finalizes scl0/sft0 (ticket cnt[0]).
// ---------------------------------------------------------------------------
__global__ __launch_bounds__(256) void k_s0y(
    const int* __restrict__ sidx, const int* __restrict__ nidx,
    const u16* __restrict__ U, const u16* __restrict__ T,
    u16* __restrict__ y0, float* __restrict__ stats, u32* __restrict__ cnt,
    const float* __restrict__ gma, const float* __restrict__ bta,
    float* __restrict__ sclG, float* __restrict__ sftG)
{
  __shared__ int isLast;
  int tid = threadIdx.x;
  int m0 = blockIdx.x * 128;
  int b = m0 >> 15;
  int c0 = (tid & 7) * 8;
  int rg = tid >> 3;
  int wv = tid >> 6;
  int mbase = m0 + rg*4;
  int p = (mbase & 32767) >> 5;
  int sp = sidx[b*NPP + p];
  u16 tv[8];
  *(uint4*)tv = *(const uint4*)(T + ((size_t)(b*NN + sp))*64 + c0);
  float tf[8], s[8], q[8];
  for (int j = 0; j < 8; ++j) { tf[j] = bf2f(tv[j]); s[j] = 0.f; q[j] = 0.f; }
  int nb[4];
  for (int i = 0; i < 4; ++i) nb[i] = nidx[mbase + i];
  for (int i = 0; i < 4; ++i) {
    u16 uv[8], ov[8];
    *(uint4*)uv = *(const uint4*)(U + ((size_t)(b*NN + nb[i]))*64 + c0);
    for (int j = 0; j < 8; ++j) {
      float d = bf2f(uv[j]) - tf[j];
      s[j] += d; q[j] += d*d;
      ov[j] = f2bf(d);
    }
    *(uint4*)(y0 + ((size_t)(mbase + i))*64 + c0) = *(uint4*)ov;
  }
  for (int msk = 8; msk <= 32; msk <<= 1)
    for (int j = 0; j < 8; ++j) {
      s[j] += __shfl_xor(s[j], msk);
      q[j] += __shfl_xor(q[j], msk);
    }
  if ((tid & 63) < 8) {
    int slot = (blockIdx.x*4 + wv) & 63;
    for (int j = 0; j < 8; ++j) {
      atomicAdd(&stats[slot*256 + c0 + j], s[j]);
      atomicAdd(&stats[SQOFF + slot*256 + c0 + j], q[j]);
    }
  }
  __syncthreads();                       // drains this block's atomics
  if (tid == 0) {
    __threadfence();
    u32 old = atomicAdd(cnt, 1u);
    isLast = (old == gridDim.x - 1);
  }
  __syncthreads();
  if (isLast && tid < H0) {
    float ss = 0.f, qq = 0.f;
    for (int sl = 0; sl < NSLOT; ++sl) {
      ss += atomicAdd(&stats[sl*256 + tid], 0.f);
      qq += atomicAdd(&stats[SQOFF + sl*256 + tid], 0.f);
    }
    float mu = ss*INV_M, var = qq*INV_M - mu*mu;
    float sc = gma[tid] * rsqrtf(var + BN_EPS);
    sclG[tid] = sc; sftG[tid] = bta[tid] - mu*sc;
  }
}

// ---------------------------------------------------------------------------
// L1 stats: stream y0, BN0+ReLU -> X0c, GEMM1 -> stats1. M=128, grid 2048.
// Last block finalizes scl1/sft1 (ticket cnt[1]).
// ---------------------------------------------------------------------------
__global__ __launch_bounds__(256) void k_l1s(
    const u16* __restrict__ y0, const u16* __restrict__ Wt1c,
    const float* __restrict__ sclG0, const float* __restrict__ sftG0,
    float* __restrict__ stOut, u32* __restrict__ cnt,
    const float* __restrict__ gma, const float* __restrict__ bta,
    float* __restrict__ sclG, float* __restrict__ sftG)
{
  __shared__ u16 X0c[8*128*8];   // 16 KB
  __shared__ u16 W1c[8*128*8];   // 16 KB
  __shared__ float scl0[64], sft0[64];
  __shared__ int isLast;
  int tid = threadIdx.x;
  int m0 = blockIdx.x * 128;

  if (tid < 64) { scl0[tid] = sclG0[tid]; sft0[tid] = sftG0[tid]; }
  for (int i = 0; i < 4; ++i)
    ((uint4*)W1c)[i*256 + tid] = ((const uint4*)Wt1c)[i*256 + tid];

  int pos = tid & 127, half = tid >> 7;
  {
    const u16* row = y0 + (size_t)(m0 + pos)*64 + half*32;
    u16 hs[32];
    for (int t = 0; t < 4; ++t) *(uint4*)&hs[t*8] = ((const uint4*)row)[t];
    __syncthreads();   // scl0 ready
    u16 ob[32];
    for (int j = 0; j < 32; ++j) {
      int c = half*32 + j;
      ob[j] = f2bf(fmaxf(fmaf(scl0[c], bf2f(hs[j]), sft0[c]), 0.f));
    }
    for (int t = 0; t < 4; ++t)
      *(uint4*)&X0c[((half*4+t)*128 + pos)*8] = *(uint4*)&ob[t*8];
  }
  __syncthreads();

  int lane = tid & 63, wv = tid >> 6, l31 = lane & 31, kh = lane >> 5;
  f32x16 acc[4];
  for (int mt = 0; mt < 4; ++mt) for (int r = 0; r < 16; ++r) acc[mt][r] = 0.f;

  for (int kt = 0; kt < 4; ++kt) {
    int ck = kt*2 + kh;
    short8 bfrag = *(const short8*)&W1c[(ck*128 + wv*32 + l31)*8];
    for (int mt = 0; mt < 4; ++mt) {
      short8 afrag = *(const short8*)&X0c[(ck*128 + mt*32 + l31)*8];
      acc[mt] = MFMA32(afrag, bfrag, acc[mt]);
    }
  }

  float s = 0.f, q = 0.f;
  for (int mt = 0; mt < 4; ++mt)
    for (int r = 0; r < 16; ++r) { float y = acc[mt][r]; s += y; q += y*y; }
  s += __shfl_xor(s, 32); q += __shfl_xor(q, 32);
  if (lane < 32) {
    int slot = (blockIdx.x*4 + wv) & 63;
    atomicAdd(&stOut[slot*256 + wv*32 + lane], s);
    atomicAdd(&stOut[SQOFF + slot*256 + wv*32 + lane], q);
  }
  __syncthreads();
  if (tid == 0) {
    __threadfence();
    u32 old = atomicAdd(cnt, 1u);
    isLast = (old == gridDim.x - 1);
  }
  __syncthreads();
  if (isLast && tid < H1) {
    float ss = 0.f, qq = 0.f;
    for (int sl = 0; sl < NSLOT; ++sl) {
      ss += atomicAdd(&stOut[sl*256 + tid], 0.f);
      qq += atomicAdd(&stOut[SQOFF + sl*256 + tid], 0.f);
    }
    float mu = ss*INV_M, var = qq*INV_M - mu*mu;
    float sc = gma[tid] * rsqrtf(var + BN_EPS);
    sclG[tid] = sc; sftG[tid] = bta[tid] - mu*sc;
  }
}

// ---------------------------------------------------------------------------
// L2 fused: stream y0 -> BN0+ReLU -> GEMM1 (A=W1,B=X0) -> BN1+ReLU -> b64
// scatter into padded X1c -> GEMM2 (W2 in 16KB quarters) -> stats2 + max/min.
// M=64, grid 4096. Last block finalizes scl2/sft2 (ticket cnt[2]).
// LDS: X1c 16.6K + A(24K: X0c 8K + W1c 16K; reused for W2 quarters) + 1.5K = 42.8K
// ---------------------------------------------------------------------------
__global__ __launch_bounds__(256) void k_l2f(
    const u16* __restrict__ y0,
    const u16* __restrict__ Wt1c, const u16* __restrict__ Wt2c,
    const float* __restrict__ sclG0, const float* __restrict__ sftG0,
    const float* __restrict__ sclG1, const float* __restrict__ sftG1,
    float* __restrict__ stOut, u16* __restrict__ mxp, u16* __restrict__ mnp,
    u32* __restrict__ cnt,
    const float* __restrict__ gma, const float* __restrict__ bta,
    float* __restrict__ sclG, float* __restrict__ sftG)
{
  __shared__ u16 X1c[16*520];    // 16.6 KB padded chunks (stride 520 u16)
  __shared__ u16 A[12288];       // 24 KB: ph1 X0c[0,4096)+W1c[4096,12288); ph2 W2 quarter
  __shared__ float scl0[64], sft0[64], scl1[128], sft1[128];
  __shared__ int isLast;
  int tid = threadIdx.x;
  int m0 = blockIdx.x * 64;

  if (tid < 64) { scl0[tid] = sclG0[tid]; sft0[tid] = sftG0[tid]; }
  if (tid < 128) { scl1[tid] = sclG1[tid]; sft1[tid] = sftG1[tid]; }
  u16* X0c = A;           // [8 kc][64 m][8]
  u16* W1c = A + 4096;    // [8 kc][128 n][8]
  for (int i = 0; i < 4; ++i)
    ((uint4*)W1c)[i*256 + tid] = ((const uint4*)Wt1c)[i*256 + tid];

  int pos = tid & 63, grp = tid >> 6;
  {
    const u16* row = y0 + (size_t)(m0 + pos)*64 + grp*16;
    u16 hs[16];
    *(uint4*)&hs[0] = ((const uint4*)row)[0];
    *(uint4*)&hs[8] = ((const uint4*)row)[1];
    __syncthreads();   // scl0/scl1 ready, W1c staged
    u16 ob[16];
    for (int j = 0; j < 16; ++j) {
      int c = grp*16 + j;
      ob[j] = f2bf(fmaxf(fmaf(scl0[c], bf2f(hs[j]), sft0[c]), 0.f));
    }
    *(uint4*)&X0c[((2*grp)*64 + pos)*8]   = *(uint4*)&ob[0];
    *(uint4*)&X0c[((2*grp+1)*64 + pos)*8] = *(uint4*)&ob[8];
  }
  __syncthreads();

  int lane = tid & 63, wv = tid >> 6, l31 = lane & 31, kh = lane >> 5;

  // ---- GEMM1 swapped: A=W1 (rows=ch), B=X0 (cols=pos) ----
  f32x16 acc1[2];
  for (int nt = 0; nt < 2; ++nt) for (int r = 0; r < 16; ++r) acc1[nt][r] = 0.f;
  for (int kt = 0; kt < 4; ++kt) {
    int ck = kt*2 + kh;
    short8 afrag = *(const short8*)&W1c[(ck*128 + wv*32 + l31)*8];
    for (int nt = 0; nt < 2; ++nt) {
      short8 bfrag = *(const short8*)&X0c[(ck*64 + nt*32 + l31)*8];
      acc1[nt] = MFMA32(afrag, bfrag, acc1[nt]);
    }
  }
  __syncthreads();   // all A-region (X0c/W1c) reads done

  // ---- BN1+ReLU + b64 scatter (4 consecutive channels per write) ----
  {
    float s1r[16], f1r[16];
    for (int r = 0; r < 16; ++r) {
      int ch = wv*32 + (r&3) + 8*(r>>2) + 4*kh;
      s1r[r] = scl1[ch]; f1r[r] = sft1[ch];
    }
    for (int nt = 0; nt < 2; ++nt) {
      int posn = nt*32 + l31;
      for (int g = 0; g < 4; ++g) {
        float v0 = fmaxf(fmaf(s1r[g*4+0], acc1[nt][g*4+0], f1r[g*4+0]), 0.f);
        float v1 = fmaxf(fmaf(s1r[g*4+1], acc1[nt][g*4+1], f1r[g*4+1]), 0.f);
        float v2 = fmaxf(fmaf(s1r[g*4+2], acc1[nt][g*4+2], f1r[g*4+2]), 0.f);
        float v3 = fmaxf(fmaf(s1r[g*4+3], acc1[nt][g*4+3], f1r[g*4+3]), 0.f);
        uint2 w = { pack2(v0, v1), pack2(v2, v3) };
        *(uint2*)&X1c[(wv*4 + g)*520 + posn*8 + 4*kh] = w;
      }
    }
  }

  // ---- GEMM2: A=X1 (rows=pos), B=W2 (cols=ch); W2 in 16KB quarters ----
  f32x16 acc2[2][2];
  for (int nt = 0; nt < 2; ++nt) for (int mt = 0; mt < 2; ++mt)
    for (int r = 0; r < 16; ++r) acc2[nt][mt][r] = 0.f;

  for (int h = 0; h < 4; ++h) {
    __syncthreads();   // prev reads of A done (h=0: GEMM1 reads; also covers scatter)
    for (int i = 0; i < 4; ++i)
      ((uint4*)A)[i*256 + tid] = ((const uint4*)Wt2c)[h*1024 + i*256 + tid];
    __syncthreads();
    for (int k4 = 0; k4 < 2; ++k4) {
      int ckw = k4*2 + kh;           // chunk within quarter
      int ckx = h*4 + ckw;           // chunk within X1c
      short8 a[2], bf_[2];
      for (int mt = 0; mt < 2; ++mt) a[mt]  = *(const short8*)&X1c[ckx*520 + (mt*32 + l31)*8];
      for (int nt = 0; nt < 2; ++nt) bf_[nt] = *(const short8*)&A[(ckw*256 + wv*64 + nt*32 + l31)*8];
      for (int nt = 0; nt < 2; ++nt)
        for (int mt = 0; mt < 2; ++mt)
          acc2[nt][mt] = MFMA32(a[mt], bf_[nt], acc2[nt][mt]);
    }
  }

  // ---- stats2 + max/min over NS (p-groups = row tiles mt) ----
  int slot = (blockIdx.x*4 + wv) & 63;
  for (int nt = 0; nt < 2; ++nt) {
    float s = 0.f, q = 0.f;
    float mx[2] = {-3.0e38f, -3.0e38f}, mn[2] = {3.0e38f, 3.0e38f};
    for (int mt = 0; mt < 2; ++mt)
      for (int r = 0; r < 16; ++r) {
        float y = acc2[nt][mt][r];
        s += y; q += y*y;
        mx[mt] = fmaxf(mx[mt], y); mn[mt] = fminf(mn[mt], y);
      }
    s += __shfl_xor(s, 32); q += __shfl_xor(q, 32);
    mx[0] = fmaxf(mx[0], __shfl_xor(mx[0], 32));
    mx[1] = fmaxf(mx[1], __shfl_xor(mx[1], 32));
    mn[0] = fminf(mn[0], __shfl_xor(mn[0], 32));
    mn[1] = fminf(mn[1], __shfl_xor(mn[1], 32));
    if (lane < 32) {
      int c = wv*64 + nt*32 + lane;
      atomicAdd(&stOut[slot*256 + c], s);
      atomicAdd(&stOut[SQOFF + slot*256 + c], q);
      for (int mt = 0; mt < 2; ++mt) {
        size_t pr = (size_t)blockIdx.x*2 + mt;
        mxp[pr*H2 + c] = f2bf(mx[mt]);
        mnp[pr*H2 + c] = f2bf(mn[mt]);
      }
    }
  }
  __syncthreads();
  if (tid == 0) {
    __threadfence();
    u32 old = atomicAdd(cnt, 1u);
    isLast = (old == gridDim.x - 1);
  }
  __syncthreads();
  if (isLast) {
    float ss = 0.f, qq = 0.f;
    for (int sl = 0; sl < NSLOT; ++sl) {
      ss += atomicAdd(&stOut[sl*256 + tid], 0.f);
      qq += atomicAdd(&stOut[SQOFF + sl*256 + tid], 0.f);
    }
    float mu = ss*INV_M, var = qq*INV_M - mu*mu;
    float sc = gma[tid] * rsqrtf(var + BN_EPS);
    sclG[tid] = sc; sftG[tid] = bta[tid] - mu*sc;
  }
}

// ---------------------------------------------------------------------------
__global__ __launch_bounds__(256) void k_final(
    const u16* __restrict__ mxp, const u16* __restrict__ mnp,
    const float* __restrict__ sclG2, const float* __restrict__ sftG2,
    float* __restrict__ out_np)
{
  __shared__ float tmp[256][33];
  int tid = threadIdx.x;
  int b = blockIdx.x >> 5;
  int p0 = (blockIdx.x & 31) * 32;

  float sc = sclG2[tid];
  float sh = sftG2[tid];

  for (int pp = 0; pp < 32; ++pp) {
    size_t base = ((size_t)(b*NPP + p0 + pp))*H2 + tid;
    float xv = bf2f(mxp[base]), nv = bf2f(mnp[base]);
    float v = (sc >= 0.f) ? fmaf(sc, xv, sh) : fmaf(sc, nv, sh);
    tmp[tid][pp] = fmaxf(v, 0.f);
  }
  __syncthreads();

  int pl = tid & 31, cg = tid >> 5;
  for (int cc = 0; cc < 32; ++cc) {
    int c = cc*8 + cg;
    out_np[((size_t)b*H2 + c)*NPP + p0 + pl] = tmp[c][pl];
  }
}

// ---------------------------------------------------------------------------
extern "C" void kernel_launch(void* const* d_in, const int* in_sizes, int n_in,
                              void* d_out, int out_size, void* d_ws, size_t ws_size,
                              hipStream_t stream)
{
  const float* xyz    = (const float*)d_in[0];
  const float* points = (const float*)d_in[1];
  const int*   sidx   = (const int*)d_in[2];
  const int*   nidx   = (const int*)d_in[3];
  const float* W0 = (const float*)d_in[4];
  const float* g0 = (const float*)d_in[6];
  const float* e0 = (const float*)d_in[7];
  const float* W1 = (const float*)d_in[8];
  const float* g1 = (const float*)d_in[10];
  const float* e1 = (const float*)d_in[11];
  const float* W2 = (const float*)d_in[12];
  const float* g2 = (const float*)d_in[14];
  const float* e2 = (const float*)d_in[15];

  float* out_xyz = (float*)d_out;
  float* out_np  = out_xyz + (size_t)BB*NPP*3;

  if (ws_size < (size_t)WS_NEED) {
    hipMemsetAsync(out_np, 0, (size_t)BB*H2*NPP*4, stream);
    k_xyz_only<<<32, 256, 0, stream>>>(xyz, sidx, out_xyz);
    return;
  }

  char* ws = (char*)d_ws;
  u32*   cnt   = (u32*)(ws + 0);
  float* stats = (float*)(ws + 256);
  u16*   Wt1c  = (u16*)(ws + 393472);
  u16*   Wt2c  = (u16*)(ws + 409856);
  float* bnc   = (float*)(ws + 475392);
  u16*   Ubuf  = (u16*)(ws + 481536);
  u16*   Tbuf  = (u16*)(ws + 4675840);
  u16*   y0    = (u16*)(ws + 8870144);
  u16*   mxp   = Ubuf;   // aliases U (dead after k_s0y)
  u16*   mnp   = Tbuf;   // aliases T
  float *scl0G = bnc,        *sft0G = bnc + 256;
  float *scl1G = bnc + 512,  *sft1G = bnc + 768;
  float *scl2G = bnc + 1024, *sft2G = bnc + 1280;

  hipMemsetAsync(ws, 0, 393472, stream);   // cnt + stats
  k_init<<<297, 256, 0, stream>>>(xyz, points, sidx, W0, W1, W2,
                                  Wt1c, Wt2c, Ubuf, Tbuf, out_xyz);
  k_s0y<<<MTOT/128, 256, 0, stream>>>(sidx, nidx, Ubuf, Tbuf, y0,
                                      stats, cnt + 0, g0, e0, scl0G, sft0G);
  k_l1s<<<MTOT/128, 256, 0, stream>>>(y0, Wt1c, scl0G, sft0G,
                                      stats + LSTRIDE, cnt + 1, g1, e1, scl1G, sft1G);
  k_l2f<<<MTOT/64, 256, 0, stream>>>(y0, Wt1c, Wt2c,
                                     scl0G, sft0G, scl1G, sft1G,
                                     stats + 2*LSTRIDE, mxp, mnp,
                                     cnt + 2, g2, e2, scl2G, sft2G);
  k_final<<<256, 256, 0, stream>>>(mxp, mnp, scl2G, sft2G, out_np);
}